// Round 5
// baseline (354.557 us; speedup 1.0000x reference)
//
#include <hip/hip_runtime.h>

#define D 512
#define NS 4096
#define NROWS 8192
#define NB_XX 272                 // 128-row x 256-col bricks covering the upper triangle
#define NB (2 * NB_XX + 512)      // 272+272+512 = 1056
#define NPB 256                   // persistent blocks (1 per CU)
#define LDSB 49152                // bytes per ring slot: 48 regions x 1KB
#define LA_OFF 0x400000u          // lo-array offset from hi-array base (4MB)

typedef __attribute__((ext_vector_type(4))) int i32x4;

__device__ __forceinline__ void gload_lds16(const void* g, void* l) {
  __builtin_amdgcn_global_load_lds(
      (const __attribute__((address_space(1))) unsigned int*)g,
      (__attribute__((address_space(3))) unsigned int*)l, 16, 0, 0);
}
#define WAITV(N) asm volatile("s_waitcnt vmcnt(" #N ")" ::: "memory")

// ---------------- k_pre: row L2 norm -> sq, i8 hi/lo fixed-point split, col partials ----
// 64 blocks x 512 threads; wave w handles rows blk*128 + w*16 + [0,16).
// X = round(xn * 2^14); h = (X+128)>>8; l = X - 256h. sq = (sum X^2) * 2^-28 (exact domain).
__global__ __launch_bounds__(512) void k_pre(const float* __restrict__ src,
                                             const float* __restrict__ tgt,
                                             float* __restrict__ sq,
                                             signed char* __restrict__ ha,
                                             signed char* __restrict__ la,
                                             float* __restrict__ Spart) {
  int t = threadIdx.x, w = t >> 6, l = t & 63;
  float csum[8] = {0.f, 0.f, 0.f, 0.f, 0.f, 0.f, 0.f, 0.f};
  for (int i = 0; i < 16; ++i) {
    int r = blockIdx.x * 128 + w * 16 + i;
    const float* p = (r < NS) ? (src + (size_t)r * D) : (tgt + (size_t)(r - NS) * D);
    float4 v0 = *(const float4*)(p + l * 8);
    float4 v1 = *(const float4*)(p + l * 8 + 4);
    float x[8] = {v0.x, v0.y, v0.z, v0.w, v1.x, v1.y, v1.z, v1.w};
    float s = 0.f;
    #pragma unroll
    for (int j = 0; j < 8; ++j) s += x[j] * x[j];
    #pragma unroll
    for (int off = 1; off < 64; off <<= 1) s += __shfl_xor(s, off);
    float iv = 1.0f / fmaxf(sqrtf(s), 1e-12f);
    signed char hs[8], ls[8];
    int sxx = 0;
    #pragma unroll
    for (int j = 0; j < 8; ++j) {
      float xn = x[j] * iv;
      int X = __float2int_rn(xn * 16384.f);
      int h = (X + 128) >> 8;
      int lo = X - (h << 8);
      hs[j] = (signed char)h;
      ls[j] = (signed char)lo;
      sxx += X * X;
      csum[j] += xn;
    }
    #pragma unroll
    for (int off = 1; off < 64; off <<= 1) sxx += __shfl_xor(sxx, off);
    if (l == 0) sq[r] = (float)((double)sxx * (1.0 / 268435456.0));
    *(uint2*)&ha[(size_t)r * 512 + l * 8] = *(uint2*)hs;
    *(uint2*)&la[(size_t)r * 512 + l * 8] = *(uint2*)ls;
  }
  __shared__ float cs[8][512];
  #pragma unroll
  for (int j = 0; j < 8; ++j) cs[w][l * 8 + j] = csum[j];
  __syncthreads();
  float a = 0.f;
  #pragma unroll
  for (int ww = 0; ww < 8; ++ww) a += cs[ww][t];
  Spart[blockIdx.x * 512 + t] = a;
}

// ---------------- k_prep: bandwidth closed form -> exp2 coefs; zero queue/accumulators --
__global__ __launch_bounds__(512) void k_prep(const float* __restrict__ sq,
                                              const float* __restrict__ Spart,
                                              float* __restrict__ na,
                                              double* __restrict__ dsum,
                                              unsigned int* __restrict__ qcnt,
                                              unsigned int* __restrict__ ccnt) {
  int t = threadIdx.x;
  double ssq = 0.0;
  for (int i = t; i < NROWS; i += 512) ssq += (double)sq[i];
  double cssum = 0.0;
  for (int b = 0; b < 64; ++b) cssum += (double)Spart[b * 512 + t];
  double ss2 = cssum * cssum;
  #pragma unroll
  for (int off = 32; off; off >>= 1) {
    ssq += __shfl_down(ssq, off);
    ss2 += __shfl_down(ss2, off);
  }
  __shared__ double l1[8], l2[8];
  if ((t & 63) == 0) { l1[t >> 6] = ssq; l2[t >> 6] = ss2; }
  __syncthreads();
  if (t == 0) {
    double SSQ = 0.0, SS2 = 0.0;
    #pragma unroll
    for (int i = 0; i < 8; ++i) { SSQ += l1[i]; SS2 += l2[i]; }
    double n = (double)NROWS;
    double sum_d2 = 2.0 * n * SSQ - 2.0 * SS2;
    double bw = sum_d2 / (n * n - n) + 1e-8;     // + EPS
    bw = bw * 0.25;                               // / KERNEL_MUL^(KERNEL_NUM//2)
    const double LOG2E = 1.4426950408889634;
    #pragma unroll
    for (int m = 0; m < 5; ++m) na[m] = (float)(-LOG2E / (bw * (double)(1 << m)));
    dsum[0] = 0.0; dsum[1] = 0.0; dsum[2] = 0.0;
    qcnt[0] = 0u; ccnt[0] = 0u;
  }
}

__device__ __forceinline__ void decode_tile(int bid, int& type, int& bi, int& c2,
                                            int& offA, int& offB, int& sym) {
  if (bid < 2 * NB_XX) {
    type = (bid >= NB_XX);
    int idx = bid - type * NB_XX;
    int b = 0;
    while (idx >= 16 - (b >> 1)) { idx -= 16 - (b >> 1); ++b; }
    bi = b; c2 = (b >> 1) + idx; sym = 1;
  } else {
    type = 2;
    int rem = bid - 2 * NB_XX;
    bi = rem >> 4; c2 = rem & 15; sym = 0;
  }
  offA = (type == 1) ? NS : 0;
  offB = (type == 0) ? 0 : NS;
}

// ---------------- k_gemm: persistent i8 fixed-point MFMA GEMM, continuous 3-slot ring ----
// 128x256 brick, 8 waves (2x4), wave = 64x64. K-step = 64. 4 i8 MFMAs -> 3 i32 accs/frag.
// LDS slot: 48 regions x 1KB: [0,8) A-h | [8,16) A-l | [16,32) B-h | [32,48) B-l.
// Swizzle (rule 21): slot holds chunk c ^ ((row>>1)&3); linear dest, pre-swizzled source.
__global__ __launch_bounds__(512, 2) void k_gemm(const signed char* __restrict__ ha,
                                                 const float* __restrict__ sq,
                                                 const float* __restrict__ na,
                                                 double* __restrict__ dsum,
                                                 unsigned int* __restrict__ qcnt,
                                                 unsigned int* __restrict__ ccnt,
                                                 float* __restrict__ out) {
  __shared__ signed char lds[3 * LDSB];
  __shared__ int tslot[2];
  __shared__ double red[8];

  int t = threadIdx.x;
  int w = t >> 6, l = t & 63;
  int wr = w >> 2, wc = w & 3;
  int fr = l & 15, fk = l >> 4;
  int rsw = (fr >> 1) & 3;

  // staging geometry (tile-independent): wave w owns regions w*6 .. w*6+5
  unsigned offc[6];
  int isb[6];
  int gsw = ((l & 3) ^ ((l >> 3) & 3)) * 16;   // pre-swizzled 16B chunk within 64B row-step
  #pragma unroll
  for (int c = 0; c < 6; ++c) {
    int r = w * 6 + c;
    int isB = (r >= 16);
    int isLo = isB ? (r >= 32) : (r >= 8);
    int rr16 = isB ? ((r - 16) & 15) : (r & 7);
    offc[c] = (isLo ? LA_OFF : 0u) + (unsigned)((rr16 * 16 + (l >> 2)) * 512 + gsw);
    isb[c] = isB;
  }
  int ldsw = w * 6 * 1024;
  int aRd = (wr * 4) * 1024 + fr * 64 + ((fk ^ rsw) * 16);           // + m*1024; A-l +8192
  int bRd = 16384 + (wc * 4) * 1024 + fr * 64 + ((fk ^ rsw) * 16);   // + n*1024; B-l +16384

  float nam0 = na[0], nam1 = na[1], nam2 = na[2], nam3 = na[3], nam4 = na[4];

  i32x4 acc1[4][4], acc2[4][4], acc3[4][4];
  i32x4 izero = {0, 0, 0, 0};
  #pragma unroll
  for (int m = 0; m < 4; ++m)
    #pragma unroll
    for (int n = 0; n < 4; ++n) { acc1[m][n] = izero; acc2[m][n] = izero; acc3[m][n] = izero; }

  double dl0 = 0.0, dl1 = 0.0, dl2 = 0.0;

  // initial two tickets
  if (t == 0) {
    tslot[0] = (int)atomicAdd(qcnt, 1u);
    tslot[1] = (int)atomicAdd(qcnt, 1u);
  }
  __syncthreads();
  int cur = __builtin_amdgcn_readfirstlane(tslot[0]);
  int nxt = __builtin_amdgcn_readfirstlane(tslot[1]);

  int typeC = 0, biC = 0, c2C = 0, oAC = 0, oBC = 0, symC = 0;
  unsigned tbA_c = 0, tbB_c = 0, tbA_n = 0, tbB_n = 0;
  if (cur < NB) {
    decode_tile(cur, typeC, biC, c2C, oAC, oBC, symC);
    tbA_c = (unsigned)(oAC + biC * 128) * 512u;
    tbB_c = (unsigned)(oBC + c2C * 256) * 512u;
  }
  if (nxt < NB) {
    int t2, b2, cc2, a2, o2, s2;
    decode_tile(nxt, t2, b2, cc2, a2, o2, s2);
    tbA_n = (unsigned)(a2 + b2 * 128) * 512u;
    tbB_n = (unsigned)(o2 + cc2 * 256) * 512u;
  }

  // prologue: stage K-steps 0,1 of first tile into slots 0,1
  if (cur < NB) {
    #pragma unroll
    for (int c = 0; c < 6; ++c)
      gload_lds16(ha + (size_t)(offc[c] + (isb[c] ? tbB_c : tbA_c)), &lds[0 + ldsw + c * 1024]);
    #pragma unroll
    for (int c = 0; c < 6; ++c)
      gload_lds16(ha + (size_t)(offc[c] + (isb[c] ? tbB_c : tbA_c) + 64u), &lds[LDSB + ldsw + c * 1024]);
  }

  unsigned sb0 = 0, sb1 = LDSB, sb2 = 2 * LDSB;
  int pend = NB;

  while (cur < NB) {
    bool nxtv = (nxt < NB);
    for (int kt = 0; kt < 8; ++kt) {
      if (kt == 7 && !nxtv) { WAITV(0); } else { WAITV(6); }
      __builtin_amdgcn_s_barrier();
      __builtin_amdgcn_sched_barrier(0);
      if (kt == 0) {
        if (t == 0) {
          int v = (int)atomicAdd(qcnt, 1u);
          tslot[0] = v;
          asm volatile("s_waitcnt lgkmcnt(0)" ::: "memory");
        }
      }
      if (kt == 1) pend = __builtin_amdgcn_readfirstlane(tslot[0]);

      // A fragment reads (held)
      i32x4 Ah[4], Al[4];
      #pragma unroll
      for (int m = 0; m < 4; ++m) {
        Ah[m] = *(const i32x4*)&lds[sb0 + aRd + m * 1024];
        Al[m] = *(const i32x4*)&lds[sb0 + 8192 + aRd + m * 1024];
      }
      // stage K-step kt+2 (this tile) or (kt+2-8) of next tile
      int st = kt + 2;
      if (st < 8) {
        #pragma unroll
        for (int c = 0; c < 6; ++c)
          gload_lds16(ha + (size_t)(offc[c] + (isb[c] ? tbB_c : tbA_c) + (unsigned)st * 64u),
                      &lds[sb2 + ldsw + c * 1024]);
      } else if (nxtv) {
        #pragma unroll
        for (int c = 0; c < 6; ++c)
          gload_lds16(ha + (size_t)(offc[c] + (isb[c] ? tbB_n : tbA_n) + (unsigned)(st - 8) * 64u),
                      &lds[sb2 + ldsw + c * 1024]);
      }
      // B fragments streamed + MFMAs
      __builtin_amdgcn_s_setprio(1);
      #pragma unroll
      for (int n = 0; n < 4; ++n) {
        i32x4 Bh = *(const i32x4*)&lds[sb0 + bRd + n * 1024];
        i32x4 Bl = *(const i32x4*)&lds[sb0 + 16384 + bRd + n * 1024];
        #pragma unroll
        for (int m = 0; m < 4; ++m) {
          acc1[m][n] = __builtin_amdgcn_mfma_i32_16x16x64_i8(Ah[m], Bh, acc1[m][n], 0, 0, 0);
          acc2[m][n] = __builtin_amdgcn_mfma_i32_16x16x64_i8(Ah[m], Bl, acc2[m][n], 0, 0, 0);
          acc2[m][n] = __builtin_amdgcn_mfma_i32_16x16x64_i8(Al[m], Bh, acc2[m][n], 0, 0, 0);
          acc3[m][n] = __builtin_amdgcn_mfma_i32_16x16x64_i8(Al[m], Bl, acc3[m][n], 0, 0, 0);
        }
      }
      __builtin_amdgcn_s_setprio(0);
      unsigned tmp = sb0; sb0 = sb1; sb1 = sb2; sb2 = tmp;
    }

    // ---- epilogue for cur: exact f64 recombine -> d2 -> 5 exp2 -> f64 accumulate ----
    {
      int giL0 = biC * 128 + wr * 64;
      int gjL0 = c2C * 256 + wc * 64;
      float sqa[4][4], sqb[4];
      #pragma unroll
      for (int m = 0; m < 4; ++m)
        #pragma unroll
        for (int j = 0; j < 4; ++j) sqa[m][j] = sq[oAC + giL0 + m * 16 + fk * 4 + j];
      #pragma unroll
      for (int n = 0; n < 4; ++n) sqb[n] = sq[oBC + gjL0 + n * 16 + fr];

      double lsum = 0.0;
      #pragma unroll
      for (int m = 0; m < 4; ++m)
        #pragma unroll
        for (int n = 0; n < 4; ++n) {
          int gjL = gjL0 + n * 16 + fr;
          #pragma unroll
          for (int j = 0; j < 4; ++j) {
            int giL = giL0 + m * 16 + fk * 4 + j;
            double tt = 65536.0 * (double)acc1[m][n][j] + 256.0 * (double)acc2[m][n][j]
                      + (double)acc3[m][n][j];
            double d2d = (double)sqa[m][j] + (double)sqb[n] - tt * 7.450580596923828e-9; // 2^-27
            float d2v = fmaxf((float)d2d, 0.f);
            float kv = __builtin_amdgcn_exp2f(d2v * nam0) + __builtin_amdgcn_exp2f(d2v * nam1)
                     + __builtin_amdgcn_exp2f(d2v * nam2) + __builtin_amdgcn_exp2f(d2v * nam3)
                     + __builtin_amdgcn_exp2f(d2v * nam4);
            float wf = symC ? ((gjL > giL) ? 2.f : ((gjL == giL) ? 1.f : 0.f)) : 1.f;
            lsum += (double)(wf * kv);
          }
        }
      if (typeC == 0) dl0 += lsum;
      else if (typeC == 1) dl1 += lsum;
      else dl2 += lsum;
      #pragma unroll
      for (int m = 0; m < 4; ++m)
        #pragma unroll
        for (int n = 0; n < 4; ++n) { acc1[m][n] = izero; acc2[m][n] = izero; acc3[m][n] = izero; }
    }

    // rotate tiles
    cur = nxt; tbA_c = tbA_n; tbB_c = tbB_n;
    nxt = pend;
    if (cur < NB) {
      decode_tile(cur, typeC, biC, c2C, oAC, oBC, symC);
      if (nxt < NB) {
        int t2, b2, cc2, a2, o2, s2;
        decode_tile(nxt, t2, b2, cc2, a2, o2, s2);
        tbA_n = (unsigned)(a2 + b2 * 128) * 512u;
        tbB_n = (unsigned)(o2 + cc2 * 256) * 512u;
      }
    }
  }

  // ---- final block reduction + global accumulate ----
  __syncthreads();
  #pragma unroll
  for (int off = 32; off; off >>= 1) {
    dl0 += __shfl_down(dl0, off);
    dl1 += __shfl_down(dl1, off);
    dl2 += __shfl_down(dl2, off);
  }
  for (int pass = 0; pass < 3; ++pass) {
    double v = (pass == 0) ? dl0 : (pass == 1) ? dl1 : dl2;
    if (l == 0) red[w] = v;
    __syncthreads();
    if (t == 0) {
      double bs = 0.0;
      #pragma unroll
      for (int i = 0; i < 8; ++i) bs += red[i];
      atomicAdd(&dsum[pass], bs);
    }
    __syncthreads();
  }
  __threadfence();
  if (t == 0) {
    unsigned tk = atomicAdd(ccnt, 1u);
    if (tk == NPB - 1) {
      __threadfence();
      double A0 = dsum[0], A1 = dsum[1], A2 = dsum[2];
      double ns = (double)NS;
      double loss = (A0 - 5.0 * ns) / (ns * (ns - 1.0))
                  + (A1 - 5.0 * ns) / (ns * (ns - 1.0))
                  - 2.0 * A2 / (ns * ns);
      out[0] = (float)loss;
    }
  }
}

extern "C" void kernel_launch(void* const* d_in, const int* in_sizes, int n_in,
                              void* d_out, int out_size, void* d_ws, size_t ws_size,
                              hipStream_t stream) {
  (void)in_sizes; (void)n_in; (void)out_size; (void)ws_size;
  const float* src = (const float*)d_in[0];
  const float* tgt = (const float*)d_in[1];
  float* out = (float*)d_out;
  char* ws = (char*)d_ws;

  // ws layout:
  float*        sq    = (float*)(ws);                      // 32 KB
  float*        Spart = (float*)(ws + 0x8000);             // 128 KB
  float*        na    = (float*)(ws + 0x28000);            // 20 B
  double*       dsum  = (double*)(ws + 0x28040);           // 24 B
  unsigned int* qcnt  = (unsigned int*)(ws + 0x28080);     // 4 B
  unsigned int* ccnt  = (unsigned int*)(ws + 0x28084);     // 4 B
  signed char*  ha    = (signed char*)(ws + 0x100000);     // 4 MB
  signed char*  la    = (signed char*)(ws + 0x500000);     // 4 MB (MUST be ha + LA_OFF)

  hipLaunchKernelGGL(k_pre, dim3(64), dim3(512), 0, stream, src, tgt, sq, ha, la, Spart);
  hipLaunchKernelGGL(k_prep, dim3(1), dim3(512), 0, stream, sq, Spart, na, dsum, qcnt, ccnt);
  hipLaunchKernelGGL(k_gemm, dim3(NPB), dim3(512), 0, stream, ha, sq, na, dsum, qcnt, ccnt, out);
}

// Round 6
// 280.535 us; speedup vs baseline: 1.2639x; 1.2639x over previous
//
#include <hip/hip_runtime.h>

#define D 512
#define NS 4096
#define NROWS 8192
#define TILES 32
#define T_SYM 528                          // 32*33/2 triangular 128x128 tiles
#define NBLK (2 * T_SYM + TILES * TILES)   // 528+528+1024 = 2080
#define LA_OFF 0x400000u                   // lo-array offset from hi-array (4 MB)

typedef __attribute__((ext_vector_type(4))) int i32x4;

__device__ __forceinline__ void gload_lds16(const void* g, void* l) {
  __builtin_amdgcn_global_load_lds(
      (const __attribute__((address_space(1))) unsigned int*)g,
      (__attribute__((address_space(3))) unsigned int*)l, 16, 0, 0);
}

// ---------------- k_pre: row norm -> sq, exact i8 hi/lo split, col partials; ----------------
// last-finishing block computes bandwidth -> na[5] (prep fused via ticket).
// 64 blocks x 512 threads; wave w handles rows blk*128 + w*16 + [0,16).
// X = round(xn*2^14); h=(X+128)>>8; l=X-256h (both i8, exact). sq = sum(X^2)*2^-28.
__global__ __launch_bounds__(512) void k_pre(const float* __restrict__ src,
                                             const float* __restrict__ tgt,
                                             float* __restrict__ sq,
                                             signed char* __restrict__ ha,
                                             signed char* __restrict__ la,
                                             float* __restrict__ Spart,
                                             float* __restrict__ na,
                                             unsigned int* __restrict__ pcnt) {
  int t = threadIdx.x, w = t >> 6, l = t & 63;
  float csum[8] = {0.f, 0.f, 0.f, 0.f, 0.f, 0.f, 0.f, 0.f};
  for (int i = 0; i < 16; ++i) {
    int r = blockIdx.x * 128 + w * 16 + i;
    const float* p = (r < NS) ? (src + (size_t)r * D) : (tgt + (size_t)(r - NS) * D);
    float4 v0 = *(const float4*)(p + l * 8);
    float4 v1 = *(const float4*)(p + l * 8 + 4);
    float x[8] = {v0.x, v0.y, v0.z, v0.w, v1.x, v1.y, v1.z, v1.w};
    float s = 0.f;
    #pragma unroll
    for (int j = 0; j < 8; ++j) s += x[j] * x[j];
    #pragma unroll
    for (int off = 1; off < 64; off <<= 1) s += __shfl_xor(s, off);
    float iv = 1.0f / fmaxf(sqrtf(s), 1e-12f);
    signed char hs[8], ls[8];
    int sxx = 0;
    #pragma unroll
    for (int j = 0; j < 8; ++j) {
      float xn = x[j] * iv;
      int X = __float2int_rn(xn * 16384.f);
      int h = (X + 128) >> 8;
      int lo = X - (h << 8);
      hs[j] = (signed char)h;
      ls[j] = (signed char)lo;
      sxx += X * X;
      csum[j] += xn;
    }
    #pragma unroll
    for (int off = 1; off < 64; off <<= 1) sxx += __shfl_xor(sxx, off);
    if (l == 0) sq[r] = (float)((double)sxx * (1.0 / 268435456.0));
    *(uint2*)&ha[(size_t)r * 512 + l * 8] = *(uint2*)hs;
    *(uint2*)&la[(size_t)r * 512 + l * 8] = *(uint2*)ls;
  }
  __shared__ float cs[8][512];
  #pragma unroll
  for (int j = 0; j < 8; ++j) cs[w][l * 8 + j] = csum[j];
  __syncthreads();
  float a = 0.f;
  #pragma unroll
  for (int ww = 0; ww < 8; ++ww) a += cs[ww][t];
  Spart[blockIdx.x * 512 + t] = a;

  // ---- last-block prep: bandwidth closed form -> exp2 coefficients ----
  __threadfence();
  __shared__ unsigned int lastFlag;
  if (t == 0) lastFlag = (atomicAdd(pcnt, 1u) == 63u) ? 1u : 0u;
  __syncthreads();
  if (lastFlag) {
    __threadfence();
    double ssq = 0.0;
    for (int i = t; i < NROWS; i += 512) ssq += (double)sq[i];
    double cssum = 0.0;
    for (int b = 0; b < 64; ++b) cssum += (double)Spart[b * 512 + t];
    double ss2 = cssum * cssum;
    #pragma unroll
    for (int off = 32; off; off >>= 1) {
      ssq += __shfl_down(ssq, off);
      ss2 += __shfl_down(ss2, off);
    }
    __shared__ double l1[8], l2[8];
    if ((t & 63) == 0) { l1[t >> 6] = ssq; l2[t >> 6] = ss2; }
    __syncthreads();
    if (t == 0) {
      double SSQ = 0.0, SS2 = 0.0;
      #pragma unroll
      for (int i = 0; i < 8; ++i) { SSQ += l1[i]; SS2 += l2[i]; }
      double n = (double)NROWS;
      double sum_d2 = 2.0 * n * SSQ - 2.0 * SS2;
      double bw = sum_d2 / (n * n - n) + 1e-8;   // + EPS
      bw = bw * 0.25;                             // / KERNEL_MUL^(KERNEL_NUM//2)
      const double LOG2E = 1.4426950408889634;
      #pragma unroll
      for (int m = 0; m < 5; ++m) na[m] = (float)(-LOG2E / (bw * (double)(1 << m)));
    }
  }
}

// ---------------- k_gemm: exact i8x4 MFMA GEMM, R3 dbuf schedule, fused epilogue --------
// 128x128 tile, 4 waves (2x2), wave = 64x64 via 4x4 16x16x64 i8 frags, K-step 64.
// LDS buffer (32 KB): Ah[128][64] | Al +8192 | Bh +16384 | Bl +24576, double-buffered.
// Swizzle (rule 21): LDS chunk q of row R holds source chunk q^((R>>1)&3); linear dest,
// pre-swizzled source, XOR on read. dot*2^28 = 65536*acc1 + 256*acc2 + acc3 (exact).
__global__ __launch_bounds__(256, 2) void k_gemm(const signed char* __restrict__ ha,
                                                 const float* __restrict__ sq,
                                                 const float* __restrict__ na,
                                                 double* __restrict__ dsum,
                                                 unsigned int* __restrict__ ccnt,
                                                 float* __restrict__ out) {
  __shared__ signed char lds[2 * 32768];
  __shared__ double red[4];

  int bid0 = blockIdx.x;
  int bid = (bid0 & 7) * (NBLK / 8) + (bid0 >> 3);   // XCD swizzle (2080 % 8 == 0)
  int type, bi, bj;
  float wgt = 1.f;
  if (bid < 2 * T_SYM) {
    type = (bid >= T_SYM);
    int idx = bid - type * T_SYM;
    bi = 0;
    while (idx >= TILES - bi) { idx -= TILES - bi; ++bi; }
    bj = bi + idx;
    wgt = (bi == bj) ? 1.f : 2.f;
  } else {
    type = 2;
    int rem = bid - 2 * T_SYM;
    bi = rem >> 5;
    bj = rem & 31;
  }
  int offA = (type == 1) ? NS : 0;
  int offB = (type == 0) ? 0 : NS;

  int t = threadIdx.x;
  int w = t >> 6, l = t & 63;
  int wr = w >> 1, wc = w & 1;
  int fr = l & 15, fk = l >> 4;

  // ---- staging: 32 regions x 1KB; wave w owns regions w*8..w*8+7 ----
  // region r: r<8 Ah rows (r&7)*16.. | r<16 Al | r<24 Bh | r<32 Bl
  int gswz = ((l & 3) ^ ((l >> 3) & 3)) * 16;      // pre-swizzled source chunk
  unsigned baseA = (unsigned)((offA + bi * 128 + (l >> 2)) * 512) + (unsigned)gswz;
  unsigned baseB = (unsigned)((offB + bj * 128 + (l >> 2)) * 512) + (unsigned)gswz;
  unsigned srcoff[8];
  #pragma unroll
  for (int c = 0; c < 8; ++c) {
    int r = w * 8 + c;
    unsigned base = (r >= 16) ? baseB : baseA;
    unsigned lofix = ((r & 8) ? LA_OFF : 0u) + (unsigned)((r & 7) * 8192);
    srcoff[c] = base + lofix;
  }
  int ldsw = w * 8192;

  int rsw = (fr >> 1) & 3;
  int aOff = wr * 4096 + fr * 64 + ((fk ^ rsw) * 16);            // Ah; +8192 Al; +m*1024
  int bOff = 16384 + wc * 4096 + fr * 64 + ((fk ^ rsw) * 16);    // Bh; +8192 Bl; +n*1024

  i32x4 acc1[4][4], acc2[4][4], acc3[4][4];
  i32x4 izero = {0, 0, 0, 0};
  #pragma unroll
  for (int m = 0; m < 4; ++m)
    #pragma unroll
    for (int n = 0; n < 4; ++n) { acc1[m][n] = izero; acc2[m][n] = izero; acc3[m][n] = izero; }

  // ---- prologue: stage K-step 0 into buf 0 ----
  #pragma unroll
  for (int c = 0; c < 8; ++c)
    gload_lds16(ha + (size_t)srcoff[c], &lds[ldsw + c * 1024]);
  __syncthreads();

  int bb = 0;
  for (int kt = 0; kt < 8; ++kt) {
    if (kt < 7) {        // issue-early: next step's loads fly over this step's MFMAs
      #pragma unroll
      for (int c = 0; c < 8; ++c)
        gload_lds16(ha + (size_t)(srcoff[c] + (unsigned)(kt + 1) * 64u),
                    &lds[(bb ^ 32768) + ldsw + c * 1024]);
    }
    __builtin_amdgcn_s_setprio(1);
    #pragma unroll
    for (int mp = 0; mp < 2; ++mp) {
      i32x4 A0h = *(const i32x4*)&lds[bb + aOff + (mp * 2) * 1024];
      i32x4 A1h = *(const i32x4*)&lds[bb + aOff + (mp * 2 + 1) * 1024];
      i32x4 A0l = *(const i32x4*)&lds[bb + 8192 + aOff + (mp * 2) * 1024];
      i32x4 A1l = *(const i32x4*)&lds[bb + 8192 + aOff + (mp * 2 + 1) * 1024];
      #pragma unroll
      for (int n = 0; n < 4; ++n) {
        i32x4 Bh = *(const i32x4*)&lds[bb + bOff + n * 1024];
        i32x4 Bl = *(const i32x4*)&lds[bb + 8192 + bOff + n * 1024];
        int m0 = mp * 2, m1 = mp * 2 + 1;
        acc1[m0][n] = __builtin_amdgcn_mfma_i32_16x16x64_i8(A0h, Bh, acc1[m0][n], 0, 0, 0);
        acc2[m0][n] = __builtin_amdgcn_mfma_i32_16x16x64_i8(A0h, Bl, acc2[m0][n], 0, 0, 0);
        acc2[m0][n] = __builtin_amdgcn_mfma_i32_16x16x64_i8(A0l, Bh, acc2[m0][n], 0, 0, 0);
        acc3[m0][n] = __builtin_amdgcn_mfma_i32_16x16x64_i8(A0l, Bl, acc3[m0][n], 0, 0, 0);
        acc1[m1][n] = __builtin_amdgcn_mfma_i32_16x16x64_i8(A1h, Bh, acc1[m1][n], 0, 0, 0);
        acc2[m1][n] = __builtin_amdgcn_mfma_i32_16x16x64_i8(A1h, Bl, acc2[m1][n], 0, 0, 0);
        acc2[m1][n] = __builtin_amdgcn_mfma_i32_16x16x64_i8(A1l, Bh, acc2[m1][n], 0, 0, 0);
        acc3[m1][n] = __builtin_amdgcn_mfma_i32_16x16x64_i8(A1l, Bl, acc3[m1][n], 0, 0, 0);
      }
    }
    __builtin_amdgcn_s_setprio(0);
    __syncthreads();   // drains vmcnt(0): publishes step kt+1; latency already hidden
    bb ^= 32768;
  }

  // ---- epilogue: exact f64 recombine -> d2 -> 5 exp2 -> f64 accumulate ----
  float nam0 = na[0], nam1 = na[1], nam2 = na[2], nam3 = na[3], nam4 = na[4];
  int gi = offA + bi * 128 + wr * 64;
  int gj = offB + bj * 128 + wc * 64;
  float sqa[4][4], sqb[4];
  #pragma unroll
  for (int m = 0; m < 4; ++m)
    #pragma unroll
    for (int j = 0; j < 4; ++j) sqa[m][j] = sq[gi + m * 16 + fk * 4 + j];
  #pragma unroll
  for (int n = 0; n < 4; ++n) sqb[n] = sq[gj + n * 16 + fr];

  double local = 0.0;
  #pragma unroll
  for (int m = 0; m < 4; ++m)
    #pragma unroll
    for (int n = 0; n < 4; ++n)
      #pragma unroll
      for (int j = 0; j < 4; ++j) {
        double tt = 65536.0 * (double)acc1[m][n][j] + 256.0 * (double)acc2[m][n][j]
                  + (double)acc3[m][n][j];
        double d2d = (double)sqa[m][j] + (double)sqb[n] - tt * 7.450580596923828e-9; // *2^-27
        float d2v = fmaxf((float)d2d, 0.f);
        float kv = __builtin_amdgcn_exp2f(d2v * nam0) + __builtin_amdgcn_exp2f(d2v * nam1)
                 + __builtin_amdgcn_exp2f(d2v * nam2) + __builtin_amdgcn_exp2f(d2v * nam3)
                 + __builtin_amdgcn_exp2f(d2v * nam4);
        local += (double)kv;
      }
  local *= (double)wgt;
  #pragma unroll
  for (int off = 32; off; off >>= 1) local += __shfl_down(local, off);
  if (l == 0) red[w] = local;
  __syncthreads();
  if (t == 0) {
    double bsum = red[0] + red[1] + red[2] + red[3];
    atomicAdd(&dsum[type], bsum);
    __threadfence();
    unsigned int ticket = atomicAdd(ccnt, 1u);
    if (ticket == NBLK - 1) {            // last block computes the loss
      __threadfence();
      double A0 = dsum[0], A1 = dsum[1], A2 = dsum[2];
      double ns = (double)NS;
      double loss = (A0 - 5.0 * ns) / (ns * (ns - 1.0))
                  + (A1 - 5.0 * ns) / (ns * (ns - 1.0))
                  - 2.0 * A2 / (ns * ns);
      out[0] = (float)loss;
    }
  }
}

extern "C" void kernel_launch(void* const* d_in, const int* in_sizes, int n_in,
                              void* d_out, int out_size, void* d_ws, size_t ws_size,
                              hipStream_t stream) {
  (void)in_sizes; (void)n_in; (void)out_size; (void)ws_size;
  const float* src = (const float*)d_in[0];
  const float* tgt = (const float*)d_in[1];
  float* out = (float*)d_out;
  char* ws = (char*)d_ws;

  // ws layout:
  float*        sq    = (float*)(ws);                      // 32 KB
  float*        Spart = (float*)(ws + 0x8000);             // 128 KB
  float*        na    = (float*)(ws + 0x28000);            // 20 B
  double*       dsum  = (double*)(ws + 0x28040);           // 24 B (zeroed)
  unsigned int* pcnt  = (unsigned int*)(ws + 0x28058);     // 4 B  (zeroed)
  unsigned int* ccnt  = (unsigned int*)(ws + 0x2805C);     // 4 B  (zeroed)
  signed char*  ha    = (signed char*)(ws + 0x100000);     // 4 MB
  signed char*  la    = (signed char*)(ws + 0x500000);     // 4 MB (MUST be ha + LA_OFF)

  hipMemsetAsync(ws + 0x28040, 0, 0x20, stream);           // dsum, pcnt, ccnt
  hipLaunchKernelGGL(k_pre, dim3(64), dim3(512), 0, stream, src, tgt, sq, ha, la, Spart, na, pcnt);
  hipLaunchKernelGGL(k_gemm, dim3(NBLK), dim3(256), 0, stream, ha, sq, na, dsum, ccnt, out);
}

// Round 7
// 251.579 us; speedup vs baseline: 1.4093x; 1.1151x over previous
//
#include <hip/hip_runtime.h>

#define D 512
#define NS 4096
#define NROWS 8192
#define TILES 32
#define T_SYM 528                          // 32*33/2 triangular 128x128 tiles
#define NBLK (2 * T_SYM + TILES * TILES)   // 528+528+1024 = 2080
#define LA_OFF 0x400000u                   // lo-array offset from hi-array (4 MB)

typedef __attribute__((ext_vector_type(4))) int i32x4;
typedef __attribute__((ext_vector_type(4))) float f32x4;

__device__ __forceinline__ void gload_lds16(const void* g, void* l) {
  __builtin_amdgcn_global_load_lds(
      (const __attribute__((address_space(1))) unsigned int*)g,
      (__attribute__((address_space(3))) unsigned int*)l, 16, 0, 0);
}

// ---------------- k_pre: row norm -> sq, exact i8 hi/lo split, col partials; ----------------
// last-finishing block computes bandwidth -> na[5] (prep fused via ticket).
// X = round(xn*2^14); h=(X+128)>>8; l=X-256h (both i8, exact). sq = sum(X^2)*2^-28.
__global__ __launch_bounds__(512) void k_pre(const float* __restrict__ src,
                                             const float* __restrict__ tgt,
                                             float* __restrict__ sq,
                                             signed char* __restrict__ ha,
                                             signed char* __restrict__ la,
                                             float* __restrict__ Spart,
                                             float* __restrict__ na,
                                             unsigned int* __restrict__ pcnt) {
  int t = threadIdx.x, w = t >> 6, l = t & 63;
  float csum[8] = {0.f, 0.f, 0.f, 0.f, 0.f, 0.f, 0.f, 0.f};
  for (int i = 0; i < 16; ++i) {
    int r = blockIdx.x * 128 + w * 16 + i;
    const float* p = (r < NS) ? (src + (size_t)r * D) : (tgt + (size_t)(r - NS) * D);
    float4 v0 = *(const float4*)(p + l * 8);
    float4 v1 = *(const float4*)(p + l * 8 + 4);
    float x[8] = {v0.x, v0.y, v0.z, v0.w, v1.x, v1.y, v1.z, v1.w};
    float s = 0.f;
    #pragma unroll
    for (int j = 0; j < 8; ++j) s += x[j] * x[j];
    #pragma unroll
    for (int off = 1; off < 64; off <<= 1) s += __shfl_xor(s, off);
    float iv = 1.0f / fmaxf(sqrtf(s), 1e-12f);
    signed char hs[8], ls[8];
    int sxx = 0;
    #pragma unroll
    for (int j = 0; j < 8; ++j) {
      float xn = x[j] * iv;
      int X = __float2int_rn(xn * 16384.f);
      int h = (X + 128) >> 8;
      int lo = X - (h << 8);
      hs[j] = (signed char)h;
      ls[j] = (signed char)lo;
      sxx += X * X;
      csum[j] += xn;
    }
    #pragma unroll
    for (int off = 1; off < 64; off <<= 1) sxx += __shfl_xor(sxx, off);
    if (l == 0) sq[r] = (float)((double)sxx * (1.0 / 268435456.0));
    *(uint2*)&ha[(size_t)r * 512 + l * 8] = *(uint2*)hs;
    *(uint2*)&la[(size_t)r * 512 + l * 8] = *(uint2*)ls;
  }
  __shared__ float cs[8][512];
  #pragma unroll
  for (int j = 0; j < 8; ++j) cs[w][l * 8 + j] = csum[j];
  __syncthreads();
  float a = 0.f;
  #pragma unroll
  for (int ww = 0; ww < 8; ++ww) a += cs[ww][t];
  Spart[blockIdx.x * 512 + t] = a;

  // ---- last-block prep: bandwidth closed form -> exp2 coefficients ----
  __threadfence();
  __shared__ unsigned int lastFlag;
  if (t == 0) lastFlag = (atomicAdd(pcnt, 1u) == 63u) ? 1u : 0u;
  __syncthreads();
  if (lastFlag) {
    __threadfence();
    double ssq = 0.0;
    for (int i = t; i < NROWS; i += 512) ssq += (double)sq[i];
    double cssum = 0.0;
    for (int b = 0; b < 64; ++b) cssum += (double)Spart[b * 512 + t];
    double ss2 = cssum * cssum;
    #pragma unroll
    for (int off = 32; off; off >>= 1) {
      ssq += __shfl_down(ssq, off);
      ss2 += __shfl_down(ss2, off);
    }
    __shared__ double l1[8], l2[8];
    if ((t & 63) == 0) { l1[t >> 6] = ssq; l2[t >> 6] = ss2; }
    __syncthreads();
    if (t == 0) {
      double SSQ = 0.0, SS2 = 0.0;
      #pragma unroll
      for (int i = 0; i < 8; ++i) { SSQ += l1[i]; SS2 += l2[i]; }
      double n = (double)NROWS;
      double sum_d2 = 2.0 * n * SSQ - 2.0 * SS2;
      double bw = sum_d2 / (n * n - n) + 1e-8;   // + EPS
      bw = bw * 0.25;                             // / KERNEL_MUL^(KERNEL_NUM//2)
      const double LOG2E = 1.4426950408889634;
      #pragma unroll
      for (int m = 0; m < 5; ++m) na[m] = (float)(-LOG2E / (bw * (double)(1 << m)));
    }
  }
}

// ---------------- k_gemm: exact i8x4 MFMA GEMM with per-K-step f32 fold ----------------
// 128x128 tile, 4 waves (2x2), wave = 64x64 via 4x4 16x16x64 i8 frags, K-step 64.
// Per frag per K-step: a1=hh, a2=hl+lh, a3=ll with C-in=0 (transient, exact, |.|<2^21),
// folded as d2f += 65536*a1 + 256*a2 + a3 (f32, cvts exact). Persistent acc = 64 regs.
// LDS buffer (32 KB): Ah[128][64] | Al +8192 | Bh +16384 | Bl +24576, double-buffered.
// Swizzle (rule 21): LDS chunk q of row R holds source chunk q^((R>>1)&3).
__global__ __launch_bounds__(256, 2) void k_gemm(const signed char* __restrict__ ha,
                                                 const float* __restrict__ sq,
                                                 const float* __restrict__ na,
                                                 double* __restrict__ dsum,
                                                 unsigned int* __restrict__ ccnt,
                                                 float* __restrict__ out) {
  __shared__ signed char lds[2 * 32768];
  __shared__ double red[4];

  int bid0 = blockIdx.x;
  int bid = (bid0 & 7) * (NBLK / 8) + (bid0 >> 3);   // XCD swizzle (2080 % 8 == 0)
  int type, bi, bj;
  float wgt = 1.f;
  if (bid < 2 * T_SYM) {
    type = (bid >= T_SYM);
    int idx = bid - type * T_SYM;
    bi = 0;
    while (idx >= TILES - bi) { idx -= TILES - bi; ++bi; }
    bj = bi + idx;
    wgt = (bi == bj) ? 1.f : 2.f;
  } else {
    type = 2;
    int rem = bid - 2 * T_SYM;
    bi = rem >> 5;
    bj = rem & 31;
  }
  int offA = (type == 1) ? NS : 0;
  int offB = (type == 0) ? 0 : NS;

  int t = threadIdx.x;
  int w = t >> 6, l = t & 63;
  int wr = w >> 1, wc = w & 1;
  int fr = l & 15, fk = l >> 4;

  // ---- staging: 32 regions x 1KB; wave w owns regions w*8..w*8+7 ----
  // region r: r<8 Ah rows (r&7)*16.. | r<16 Al | r<24 Bh | r<32 Bl
  int gswz = ((l & 3) ^ ((l >> 3) & 3)) * 16;      // pre-swizzled source chunk
  unsigned baseA = (unsigned)((offA + bi * 128 + (l >> 2)) * 512) + (unsigned)gswz;
  unsigned baseB = (unsigned)((offB + bj * 128 + (l >> 2)) * 512) + (unsigned)gswz;
  unsigned srcoff[8];
  #pragma unroll
  for (int c = 0; c < 8; ++c) {
    int r = w * 8 + c;
    unsigned base = (r >= 16) ? baseB : baseA;
    unsigned lofix = ((r & 8) ? LA_OFF : 0u) + (unsigned)((r & 7) * 8192);
    srcoff[c] = base + lofix;
  }
  int ldsw = w * 8192;

  int rsw = (fr >> 1) & 3;
  int aOff = wr * 4096 + fr * 64 + ((fk ^ rsw) * 16);            // Ah; +8192 Al; +m*1024
  int bOff = 16384 + wc * 4096 + fr * 64 + ((fk ^ rsw) * 16);    // Bh; +8192 Bl; +n*1024

  f32x4 d2f[4][4];
  f32x4 fzero = {0.f, 0.f, 0.f, 0.f};
  i32x4 izero = {0, 0, 0, 0};
  #pragma unroll
  for (int m = 0; m < 4; ++m)
    #pragma unroll
    for (int n = 0; n < 4; ++n) d2f[m][n] = fzero;

  // ---- prologue: stage K-step 0 into buf 0 ----
  #pragma unroll
  for (int c = 0; c < 8; ++c)
    gload_lds16(ha + (size_t)srcoff[c], &lds[ldsw + c * 1024]);
  __syncthreads();

  int bb = 0;
  for (int kt = 0; kt < 8; ++kt) {
    if (kt < 7) {        // issue-early: next step's loads fly over this step's MFMAs
      #pragma unroll
      for (int c = 0; c < 8; ++c)
        gload_lds16(ha + (size_t)(srcoff[c] + (unsigned)(kt + 1) * 64u),
                    &lds[(bb ^ 32768) + ldsw + c * 1024]);
    }
    i32x4 Ah[4], Al[4];
    #pragma unroll
    for (int m = 0; m < 4; ++m) {
      Ah[m] = *(const i32x4*)&lds[bb + aOff + m * 1024];
      Al[m] = *(const i32x4*)&lds[bb + 8192 + aOff + m * 1024];
    }
    __builtin_amdgcn_s_setprio(1);
    #pragma unroll
    for (int n = 0; n < 4; ++n) {
      i32x4 Bh = *(const i32x4*)&lds[bb + bOff + n * 1024];
      i32x4 Bl = *(const i32x4*)&lds[bb + 8192 + bOff + n * 1024];
      #pragma unroll
      for (int m = 0; m < 4; ++m) {
        i32x4 a1 = __builtin_amdgcn_mfma_i32_16x16x64_i8(Ah[m], Bh, izero, 0, 0, 0);
        i32x4 a2 = __builtin_amdgcn_mfma_i32_16x16x64_i8(Ah[m], Bl, izero, 0, 0, 0);
        a2 = __builtin_amdgcn_mfma_i32_16x16x64_i8(Al[m], Bh, a2, 0, 0, 0);
        i32x4 a3 = __builtin_amdgcn_mfma_i32_16x16x64_i8(Al[m], Bl, izero, 0, 0, 0);
        #pragma unroll
        for (int j = 0; j < 4; ++j)
          d2f[m][n][j] += fmaf(65536.f, (float)a1[j], fmaf(256.f, (float)a2[j], (float)a3[j]));
      }
    }
    __builtin_amdgcn_s_setprio(0);
    __syncthreads();   // drains vmcnt(0): publishes step kt+1; latency already hidden
    bb ^= 32768;
  }

  // ---- epilogue: d2 -> 5 exp2 -> f64 accumulate ----
  float nam0 = na[0], nam1 = na[1], nam2 = na[2], nam3 = na[3], nam4 = na[4];
  int gi = offA + bi * 128 + wr * 64;
  int gj = offB + bj * 128 + wc * 64;
  float sqa[4][4], sqb[4];
  #pragma unroll
  for (int m = 0; m < 4; ++m)
    #pragma unroll
    for (int j = 0; j < 4; ++j) sqa[m][j] = sq[gi + m * 16 + fk * 4 + j];
  #pragma unroll
  for (int n = 0; n < 4; ++n) sqb[n] = sq[gj + n * 16 + fr];

  double local = 0.0;
  #pragma unroll
  for (int m = 0; m < 4; ++m)
    #pragma unroll
    for (int n = 0; n < 4; ++n)
      #pragma unroll
      for (int j = 0; j < 4; ++j) {
        // d2 = sqa + sqb - 2*dot, dot*2^28 = d2f  =>  d2 = sqa+sqb - d2f*2^-27
        float d2v = fmaxf(fmaf(-7.450580596923828e-9f, d2f[m][n][j], sqa[m][j] + sqb[n]), 0.f);
        float kv = __builtin_amdgcn_exp2f(d2v * nam0) + __builtin_amdgcn_exp2f(d2v * nam1)
                 + __builtin_amdgcn_exp2f(d2v * nam2) + __builtin_amdgcn_exp2f(d2v * nam3)
                 + __builtin_amdgcn_exp2f(d2v * nam4);
        local += (double)kv;
      }
  local *= (double)wgt;
  #pragma unroll
  for (int off = 32; off; off >>= 1) local += __shfl_down(local, off);
  if (l == 0) red[w] = local;
  __syncthreads();
  if (t == 0) {
    double bsum = red[0] + red[1] + red[2] + red[3];
    atomicAdd(&dsum[type], bsum);
    __threadfence();
    unsigned int ticket = atomicAdd(ccnt, 1u);
    if (ticket == NBLK - 1) {            // last block computes the loss
      __threadfence();
      double A0 = dsum[0], A1 = dsum[1], A2 = dsum[2];
      double ns = (double)NS;
      double loss = (A0 - 5.0 * ns) / (ns * (ns - 1.0))
                  + (A1 - 5.0 * ns) / (ns * (ns - 1.0))
                  - 2.0 * A2 / (ns * ns);
      out[0] = (float)loss;
    }
  }
}

extern "C" void kernel_launch(void* const* d_in, const int* in_sizes, int n_in,
                              void* d_out, int out_size, void* d_ws, size_t ws_size,
                              hipStream_t stream) {
  (void)in_sizes; (void)n_in; (void)out_size; (void)ws_size;
  const float* src = (const float*)d_in[0];
  const float* tgt = (const float*)d_in[1];
  float* out = (float*)d_out;
  char* ws = (char*)d_ws;

  // ws layout:
  float*        sq    = (float*)(ws);                      // 32 KB
  float*        Spart = (float*)(ws + 0x8000);             // 128 KB
  float*        na    = (float*)(ws + 0x28000);            // 20 B
  double*       dsum  = (double*)(ws + 0x28040);           // 24 B (zeroed)
  unsigned int* pcnt  = (unsigned int*)(ws + 0x28058);     // 4 B  (zeroed)
  unsigned int* ccnt  = (unsigned int*)(ws + 0x2805C);     // 4 B  (zeroed)
  signed char*  ha    = (signed char*)(ws + 0x100000);     // 4 MB
  signed char*  la    = (signed char*)(ws + 0x500000);     // 4 MB (MUST be ha + LA_OFF)

  hipMemsetAsync(ws + 0x28040, 0, 0x20, stream);           // dsum, pcnt, ccnt
  hipLaunchKernelGGL(k_pre, dim3(64), dim3(512), 0, stream, src, tgt, sq, ha, la, Spart, na, pcnt);
  hipLaunchKernelGGL(k_gemm, dim3(NBLK), dim3(256), 0, stream, ha, sq, na, dsum, ccnt, out);
}

// Round 8
// 246.163 us; speedup vs baseline: 1.4403x; 1.0220x over previous
//
#include <hip/hip_runtime.h>

#define D 512
#define NS 4096
#define NROWS 8192
#define TILES 32
#define T_SYM 528                          // 32*33/2 triangular 128x128 tiles
#define NBLK (2 * T_SYM + TILES * TILES)   // 528+528+1024 = 2080
#define LA_OFF 0x400000u                   // lo-array offset from hi-array (4 MB)

typedef __attribute__((ext_vector_type(4))) int i32x4;

__device__ __forceinline__ void gload_lds16(const void* g, void* l) {
  __builtin_amdgcn_global_load_lds(
      (const __attribute__((address_space(1))) unsigned int*)g,
      (__attribute__((address_space(3))) unsigned int*)l, 16, 0, 0);
}

// ---------------- k_pre: row norm -> sq, exact i8 hi/lo split, col partials; ----------------
// last-finishing block computes bandwidth -> na[5] (prep fused via ticket).
// X = round(xn*2^14); h=(X+128)>>8; l=X-256h (both i8, exact). sq = sum(X^2)*2^-28.
__global__ __launch_bounds__(512) void k_pre(const float* __restrict__ src,
                                             const float* __restrict__ tgt,
                                             float* __restrict__ sq,
                                             signed char* __restrict__ ha,
                                             signed char* __restrict__ la,
                                             float* __restrict__ Spart,
                                             float* __restrict__ na,
                                             unsigned int* __restrict__ pcnt) {
  int t = threadIdx.x, w = t >> 6, l = t & 63;
  float csum[8] = {0.f, 0.f, 0.f, 0.f, 0.f, 0.f, 0.f, 0.f};
  for (int i = 0; i < 16; ++i) {
    int r = blockIdx.x * 128 + w * 16 + i;
    const float* p = (r < NS) ? (src + (size_t)r * D) : (tgt + (size_t)(r - NS) * D);
    float4 v0 = *(const float4*)(p + l * 8);
    float4 v1 = *(const float4*)(p + l * 8 + 4);
    float x[8] = {v0.x, v0.y, v0.z, v0.w, v1.x, v1.y, v1.z, v1.w};
    float s = 0.f;
    #pragma unroll
    for (int j = 0; j < 8; ++j) s += x[j] * x[j];
    #pragma unroll
    for (int off = 1; off < 64; off <<= 1) s += __shfl_xor(s, off);
    float iv = 1.0f / fmaxf(sqrtf(s), 1e-12f);
    signed char hs[8], ls[8];
    int sxx = 0;
    #pragma unroll
    for (int j = 0; j < 8; ++j) {
      float xn = x[j] * iv;
      int X = __float2int_rn(xn * 16384.f);
      int h = (X + 128) >> 8;
      int lo = X - (h << 8);
      hs[j] = (signed char)h;
      ls[j] = (signed char)lo;
      sxx += X * X;
      csum[j] += xn;
    }
    #pragma unroll
    for (int off = 1; off < 64; off <<= 1) sxx += __shfl_xor(sxx, off);
    if (l == 0) sq[r] = (float)((double)sxx * (1.0 / 268435456.0));
    *(uint2*)&ha[(size_t)r * 512 + l * 8] = *(uint2*)hs;
    *(uint2*)&la[(size_t)r * 512 + l * 8] = *(uint2*)ls;
  }
  __shared__ float cs[8][512];
  #pragma unroll
  for (int j = 0; j < 8; ++j) cs[w][l * 8 + j] = csum[j];
  __syncthreads();
  float a = 0.f;
  #pragma unroll
  for (int ww = 0; ww < 8; ++ww) a += cs[ww][t];
  Spart[blockIdx.x * 512 + t] = a;

  // ---- last-block prep: bandwidth closed form -> exp2 coefficients ----
  __threadfence();
  __shared__ unsigned int lastFlag;
  if (t == 0) lastFlag = (atomicAdd(pcnt, 1u) == 63u) ? 1u : 0u;
  __syncthreads();
  if (lastFlag) {
    __threadfence();
    double ssq = 0.0;
    for (int i = t; i < NROWS; i += 512) ssq += (double)sq[i];
    double cssum = 0.0;
    for (int b = 0; b < 64; ++b) cssum += (double)Spart[b * 512 + t];
    double ss2 = cssum * cssum;
    #pragma unroll
    for (int off = 32; off; off >>= 1) {
      ssq += __shfl_down(ssq, off);
      ss2 += __shfl_down(ss2, off);
    }
    __shared__ double l1[8], l2[8];
    if ((t & 63) == 0) { l1[t >> 6] = ssq; l2[t >> 6] = ss2; }
    __syncthreads();
    if (t == 0) {
      double SSQ = 0.0, SS2 = 0.0;
      #pragma unroll
      for (int i = 0; i < 8; ++i) { SSQ += l1[i]; SS2 += l2[i]; }
      double n = (double)NROWS;
      double sum_d2 = 2.0 * n * SSQ - 2.0 * SS2;
      double bw = sum_d2 / (n * n - n) + 1e-8;   // + EPS
      bw = bw * 0.25;                             // / KERNEL_MUL^(KERNEL_NUM//2)
      const double LOG2E = 1.4426950408889634;
      #pragma unroll
      for (int m = 0; m < 5; ++m) na[m] = (float)(-LOG2E / (bw * (double)(1 << m)));
    }
  }
}

// ---------------- k_gemm: fold-free i8x4 MFMA GEMM, 1 wave/SIMD, 512-VGPR budget ----------
// 128x128 tile, 4 waves (2x2), wave = 64x64 via 4x4 16x16x64 i8 frags, K-step 64.
// acc1(hh), acc2(hl+lh), acc3(ll) persist in i32 across ALL of K (no overflow: <2^24),
// recombined once in the epilogue: tt = 65536*a1 + 256*a2 + a3 (f32 fold, cvts exact).
// LDS buffer (32 KB): Ah[128][64] | Al +8192 | Bh +16384 | Bl +24576, double-buffered.
// Swizzle (rule 21): LDS chunk q of row R holds source chunk q^((R>>1)&3).
__global__ __launch_bounds__(256, 1) void k_gemm(const signed char* __restrict__ ha,
                                                 const float* __restrict__ sq,
                                                 const float* __restrict__ na,
                                                 double* __restrict__ dsum,
                                                 unsigned int* __restrict__ ccnt,
                                                 float* __restrict__ out) {
  __shared__ signed char lds[2 * 32768];
  __shared__ double red[4];

  int bid0 = blockIdx.x;
  int bid = (bid0 & 7) * (NBLK / 8) + (bid0 >> 3);   // XCD swizzle (2080 % 8 == 0)
  int type, bi, bj;
  float wgt = 1.f;
  if (bid < 2 * T_SYM) {
    type = (bid >= T_SYM);
    int idx = bid - type * T_SYM;
    bi = 0;
    while (idx >= TILES - bi) { idx -= TILES - bi; ++bi; }
    bj = bi + idx;
    wgt = (bi == bj) ? 1.f : 2.f;
  } else {
    type = 2;
    int rem = bid - 2 * T_SYM;
    bi = rem >> 5;
    bj = rem & 31;
  }
  int offA = (type == 1) ? NS : 0;
  int offB = (type == 0) ? 0 : NS;

  int t = threadIdx.x;
  int w = t >> 6, l = t & 63;
  int wr = w >> 1, wc = w & 1;
  int fr = l & 15, fk = l >> 4;

  // ---- staging: 32 regions x 1KB; wave w owns regions w*8..w*8+7 ----
  // region r: r<8 Ah rows (r&7)*16.. | r<16 Al | r<24 Bh | r<32 Bl
  int gswz = ((l & 3) ^ ((l >> 3) & 3)) * 16;      // pre-swizzled source chunk
  unsigned baseA = (unsigned)((offA + bi * 128 + (l >> 2)) * 512) + (unsigned)gswz;
  unsigned baseB = (unsigned)((offB + bj * 128 + (l >> 2)) * 512) + (unsigned)gswz;
  unsigned srcoff[8];
  #pragma unroll
  for (int c = 0; c < 8; ++c) {
    int r = w * 8 + c;
    unsigned base = (r >= 16) ? baseB : baseA;
    unsigned lofix = ((r & 8) ? LA_OFF : 0u) + (unsigned)((r & 7) * 8192);
    srcoff[c] = base + lofix;
  }
  int ldsw = w * 8192;

  int rsw = (fr >> 1) & 3;
  int aOff = wr * 4096 + fr * 64 + ((fk ^ rsw) * 16);            // Ah; +8192 Al; +m*1024
  int bOff = 16384 + wc * 4096 + fr * 64 + ((fk ^ rsw) * 16);    // Bh; +8192 Bl; +n*1024

  i32x4 acc1[4][4], acc2[4][4], acc3[4][4];
  i32x4 izero = {0, 0, 0, 0};
  #pragma unroll
  for (int m = 0; m < 4; ++m)
    #pragma unroll
    for (int n = 0; n < 4; ++n) { acc1[m][n] = izero; acc2[m][n] = izero; acc3[m][n] = izero; }

  // ---- prologue: stage K-step 0 into buf 0 ----
  #pragma unroll
  for (int c = 0; c < 8; ++c)
    gload_lds16(ha + (size_t)srcoff[c], &lds[ldsw + c * 1024]);
  __syncthreads();

  int bb = 0;
  for (int kt = 0; kt < 8; ++kt) {
    if (kt < 7) {        // issue-early: next step's loads fly over this step's MFMAs
      #pragma unroll
      for (int c = 0; c < 8; ++c)
        gload_lds16(ha + (size_t)(srcoff[c] + (unsigned)(kt + 1) * 64u),
                    &lds[(bb ^ 32768) + ldsw + c * 1024]);
    }
    i32x4 Ah[4], Al[4];
    #pragma unroll
    for (int m = 0; m < 4; ++m) {
      Ah[m] = *(const i32x4*)&lds[bb + aOff + m * 1024];
      Al[m] = *(const i32x4*)&lds[bb + 8192 + aOff + m * 1024];
    }
    #pragma unroll
    for (int n = 0; n < 4; ++n) {
      i32x4 Bh = *(const i32x4*)&lds[bb + bOff + n * 1024];
      i32x4 Bl = *(const i32x4*)&lds[bb + 8192 + bOff + n * 1024];
      #pragma unroll
      for (int m = 0; m < 4; ++m) {
        acc1[m][n] = __builtin_amdgcn_mfma_i32_16x16x64_i8(Ah[m], Bh, acc1[m][n], 0, 0, 0);
        acc2[m][n] = __builtin_amdgcn_mfma_i32_16x16x64_i8(Ah[m], Bl, acc2[m][n], 0, 0, 0);
        acc2[m][n] = __builtin_amdgcn_mfma_i32_16x16x64_i8(Al[m], Bh, acc2[m][n], 0, 0, 0);
        acc3[m][n] = __builtin_amdgcn_mfma_i32_16x16x64_i8(Al[m], Bl, acc3[m][n], 0, 0, 0);
      }
    }
    __syncthreads();   // drains vmcnt(0): publishes step kt+1; latency already hidden
    bb ^= 32768;
  }

  // ---- epilogue: f32 fold (exact cvts) -> d2 -> 5 exp2 -> f64 accumulate ----
  float nam0 = na[0], nam1 = na[1], nam2 = na[2], nam3 = na[3], nam4 = na[4];
  int gi = offA + bi * 128 + wr * 64;
  int gj = offB + bj * 128 + wc * 64;
  float sqa[4][4], sqb[4];
  #pragma unroll
  for (int m = 0; m < 4; ++m)
    #pragma unroll
    for (int j = 0; j < 4; ++j) sqa[m][j] = sq[gi + m * 16 + fk * 4 + j];
  #pragma unroll
  for (int n = 0; n < 4; ++n) sqb[n] = sq[gj + n * 16 + fr];

  double local = 0.0;
  #pragma unroll
  for (int m = 0; m < 4; ++m)
    #pragma unroll
    for (int n = 0; n < 4; ++n)
      #pragma unroll
      for (int j = 0; j < 4; ++j) {
        float tt = fmaf(65536.f, (float)acc1[m][n][j],
                        fmaf(256.f, (float)acc2[m][n][j], (float)acc3[m][n][j]));
        // d2 = sqa + sqb - 2*dot, dot = tt*2^-28  =>  d2 = sqa+sqb - tt*2^-27
        float d2v = fmaxf(fmaf(-7.450580596923828e-9f, tt, sqa[m][j] + sqb[n]), 0.f);
        float kv = __builtin_amdgcn_exp2f(d2v * nam0) + __builtin_amdgcn_exp2f(d2v * nam1)
                 + __builtin_amdgcn_exp2f(d2v * nam2) + __builtin_amdgcn_exp2f(d2v * nam3)
                 + __builtin_amdgcn_exp2f(d2v * nam4);
        local += (double)kv;
      }
  local *= (double)wgt;
  #pragma unroll
  for (int off = 32; off; off >>= 1) local += __shfl_down(local, off);
  if (l == 0) red[w] = local;
  __syncthreads();
  if (t == 0) {
    double bsum = red[0] + red[1] + red[2] + red[3];
    atomicAdd(&dsum[type], bsum);
    __threadfence();
    unsigned int ticket = atomicAdd(ccnt, 1u);
    if (ticket == NBLK - 1) {            // last block computes the loss
      __threadfence();
      double A0 = dsum[0], A1 = dsum[1], A2 = dsum[2];
      double ns = (double)NS;
      double loss = (A0 - 5.0 * ns) / (ns * (ns - 1.0))
                  + (A1 - 5.0 * ns) / (ns * (ns - 1.0))
                  - 2.0 * A2 / (ns * ns);
      out[0] = (float)loss;
    }
  }
}

extern "C" void kernel_launch(void* const* d_in, const int* in_sizes, int n_in,
                              void* d_out, int out_size, void* d_ws, size_t ws_size,
                              hipStream_t stream) {
  (void)in_sizes; (void)n_in; (void)out_size; (void)ws_size;
  const float* src = (const float*)d_in[0];
  const float* tgt = (const float*)d_in[1];
  float* out = (float*)d_out;
  char* ws = (char*)d_ws;

  // ws layout:
  float*        sq    = (float*)(ws);                      // 32 KB
  float*        Spart = (float*)(ws + 0x8000);             // 128 KB
  float*        na    = (float*)(ws + 0x28000);            // 20 B
  double*       dsum  = (double*)(ws + 0x28040);           // 24 B (zeroed)
  unsigned int* pcnt  = (unsigned int*)(ws + 0x28058);     // 4 B  (zeroed)
  unsigned int* ccnt  = (unsigned int*)(ws + 0x2805C);     // 4 B  (zeroed)
  signed char*  ha    = (signed char*)(ws + 0x100000);     // 4 MB
  signed char*  la    = (signed char*)(ws + 0x500000);     // 4 MB (MUST be ha + LA_OFF)

  hipMemsetAsync(ws + 0x28040, 0, 0x20, stream);           // dsum, pcnt, ccnt
  hipLaunchKernelGGL(k_pre, dim3(64), dim3(512), 0, stream, src, tgt, sq, ha, la, Spart, na, pcnt);
  hipLaunchKernelGGL(k_gemm, dim3(NBLK), dim3(256), 0, stream, ha, sq, na, dsum, ccnt, out);
}